// Round 1
// baseline (2717.346 us; speedup 1.0000x reference)
//
#include <hip/hip_runtime.h>
#include <hip/hip_bf16.h>

// IPA constants
constexpr float W_C_ = 0.23570226039551584f;  // sqrt(2/(9*4))
constexpr float W_L_ = 0.5773502691896258f;   // sqrt(1/3)
constexpr float INV_SQRT_C_ = 0.25f;          // 16^-0.5

// ---------------------------------------------------------------------------
// Generic 32x32-tile f32 GEMM: Co[M,N] = A[M,K] @ B[K,N] (+ bias[N])
// M,N,K all multiples of 32. 256 threads, 2x2 micro-tile.
// ---------------------------------------------------------------------------
__global__ __launch_bounds__(256) void gemm_tiled(
    const float* __restrict__ A, const float* __restrict__ B,
    const float* __restrict__ bias, float* __restrict__ Co,
    int M, int N, int K) {
  __shared__ float As[32][33];
  __shared__ float Bs[32][33];
  const int bi = blockIdx.y * 32, bj = blockIdx.x * 32;
  const int t = threadIdx.x;
  const int ty = t >> 4, tx = t & 15;
  float acc00 = 0.f, acc01 = 0.f, acc10 = 0.f, acc11 = 0.f;
  for (int k0 = 0; k0 < K; k0 += 32) {
#pragma unroll
    for (int q = 0; q < 4; q++) {
      int idx = t + q * 256;
      int r = idx >> 5, c = idx & 31;
      As[r][c] = A[(size_t)(bi + r) * K + k0 + c];
      Bs[r][c] = B[(size_t)(k0 + r) * N + bj + c];
    }
    __syncthreads();
#pragma unroll
    for (int kk = 0; kk < 32; kk++) {
      float a0 = As[ty * 2][kk], a1 = As[ty * 2 + 1][kk];
      float b0 = Bs[kk][tx * 2], b1 = Bs[kk][tx * 2 + 1];
      acc00 += a0 * b0; acc01 += a0 * b1;
      acc10 += a1 * b0; acc11 += a1 * b1;
    }
    __syncthreads();
  }
  int r0 = bi + ty * 2, c0 = bj + tx * 2;
  float bb0 = bias ? bias[c0] : 0.f;
  float bb1 = bias ? bias[c0 + 1] : 0.f;
  Co[(size_t)r0 * N + c0] = acc00 + bb0;
  Co[(size_t)r0 * N + c0 + 1] = acc01 + bb1;
  Co[(size_t)(r0 + 1) * N + c0] = acc10 + bb0;
  Co[(size_t)(r0 + 1) * N + c0 + 1] = acc11 + bb1;
}

// ---------------------------------------------------------------------------
// Prep: reshape projections, apply frames to points, compute sq/sk.
// Layouts: qbuf/kbuf [n][h*16+c]; v2buf [n][h*40 + e] (e<16: v[c], e>=16:
// vg[p*3+x]); qgbuf/kgbuf [n][h*12 + p*3+x]; sqbuf/skbuf [n][h].
// ---------------------------------------------------------------------------
__global__ __launch_bounds__(256) void prep_kernel(
    const float* __restrict__ projQKV, const float* __restrict__ projQKP,
    const float* __restrict__ projVP, const float* __restrict__ fR,
    const float* __restrict__ ft,
    float* __restrict__ qbuf, float* __restrict__ kbuf, float* __restrict__ v2buf,
    float* __restrict__ qgbuf, float* __restrict__ kgbuf,
    float* __restrict__ sqbuf, float* __restrict__ skbuf) {
  const int n = blockIdx.x, t = threadIdx.x;
  __shared__ float R[9], tt[3];
  __shared__ float qgL[144], kgL[144];
  if (t < 9) R[t] = fR[n * 9 + t];
  if (t < 3) tt[t] = ft[n * 3 + t];
  __syncthreads();
  const float* rQKV = projQKV + (size_t)n * 576;
  const float* rQKP = projQKP + (size_t)n * 288;
  const float* rVP = projVP + (size_t)n * 288;
  if (t < 192) {
    int h = t >> 4, c = t & 15;
    qbuf[(size_t)n * 192 + t] = rQKV[c * 12 + h];
    kbuf[(size_t)n * 192 + t] = rQKV[192 + c * 12 + h];
    v2buf[(size_t)n * 480 + h * 40 + c] = rQKV[384 + c * 12 + h];
  }
  if (t < 144) {
    int e = t / 12, h = t % 12;  // e = p*3+x
    int p = e / 3, x = e % 3;
    float aq = tt[x], ak = tt[x];
#pragma unroll
    for (int y = 0; y < 3; y++) {
      float r = R[x * 3 + y];
      aq += r * rQKP[p * 36 + y * 12 + h];
      ak += r * rQKP[144 + p * 36 + y * 12 + h];
    }
    qgL[h * 12 + e] = aq;
    kgL[h * 12 + e] = ak;
    qgbuf[(size_t)n * 144 + h * 12 + e] = aq;
    kgbuf[(size_t)n * 144 + h * 12 + e] = ak;
  }
  for (int idx = t; idx < 288; idx += 256) {
    int e = idx / 12, h = idx % 12;  // e = p*3+x, p<8
    int p = e / 3, x = e % 3;
    float a = tt[x];
#pragma unroll
    for (int y = 0; y < 3; y++) a += R[x * 3 + y] * rVP[p * 36 + y * 12 + h];
    v2buf[(size_t)n * 480 + h * 40 + 16 + e] = a;
  }
  __syncthreads();
  if (t < 12) {
    float s = 0.f;
#pragma unroll
    for (int e = 0; e < 12; e++) { float v = qgL[t * 12 + e]; s += v * v; }
    sqbuf[n * 12 + t] = s;
  } else if (t < 24) {
    int h = t - 12;
    float s = 0.f;
#pragma unroll
    for (int e = 0; e < 12; e++) { float v = kgL[h * 12 + e]; s += v * v; }
    skbuf[n * 12 + h] = s;
  }
}

// ---------------------------------------------------------------------------
// Main fused IPA kernel: one block per query residue i. Flash-style online
// softmax over j so pair_rep is read exactly ONCE. Writes feats[i][2112].
// ---------------------------------------------------------------------------
__global__ __launch_bounds__(256) void ipa_main(
    const float* __restrict__ pair, const float* __restrict__ W_b,
    const float* __restrict__ gamma, const float* __restrict__ fR,
    const float* __restrict__ ft,
    const float* __restrict__ qbuf, const float* __restrict__ kbuf,
    const float* __restrict__ v2buf, const float* __restrict__ qgbuf,
    const float* __restrict__ kgbuf, const float* __restrict__ sqbuf,
    const float* __restrict__ skbuf, float* __restrict__ feats) {
  const int i = blockIdx.x, t = threadIdx.x;
  __shared__ float pairT[16][132];   // padded: 132*4B = 33 banks-ish, 16B aligned rows
  __shared__ float WtL[12][128];     // W_b transposed [h][d]
  __shared__ float qL[12][16];
  __shared__ float qgL[12][12];
  __shared__ float bbL[16][12];      // pair-bias per (jl, h)
  __shared__ float pbT[16][12];      // softmax numerators p per (jl, h)
  __shared__ float mL[12], lL[12], rL[12], hwL[12], sqL[12];
  __shared__ float oaccL[12][40];
  __shared__ float RL[9], ttL[3];

  // ---- init ----
  for (int idx = t; idx < 1536; idx += 256) {
    int d = idx / 12, h = idx % 12;
    WtL[h][d] = W_b[idx];  // W_b[d*12+h]
  }
  if (t < 192) qL[t >> 4][t & 15] = qbuf[(size_t)i * 192 + t];
  if (t < 144) qgL[t / 12][t % 12] = qgbuf[(size_t)i * 144 + t];
  if (t < 12) {
    float g = gamma[t];
    hwL[t] = fmaxf(g, 0.f) + log1pf(expf(-fabsf(g)));  // softplus
    sqL[t] = sqbuf[i * 12 + t];
    mL[t] = -1e30f;
    lL[t] = 0.f;
  }
  if (t < 9) RL[t] = fR[i * 9 + t];
  if (t < 3) ttL[t] = ft[i * 3 + t];
  __syncthreads();

  // hoist this thread's W_b slice (8 d-values x 12 h) into registers
  const int jl = t >> 4, dq = t & 15;
  float4 wreg[12][2];
#pragma unroll
  for (int h = 0; h < 12; h++) {
    const float4* w4 = (const float4*)&WtL[h][dq * 8];
    wreg[h][0] = w4[0];
    wreg[h][1] = w4[1];
  }

  float opacc[12];  // used by t<128: o_pair[h][d=t]
  float ovacc[4];   // used by t>=128: o/og outputs u+g*128
  int oh[4];
  const int u = t - 128;
#pragma unroll
  for (int h = 0; h < 12; h++) opacc[h] = 0.f;
#pragma unroll
  for (int g = 0; g < 4; g++) {
    ovacc[g] = 0.f;
    int o = u + g * 128;
    oh[g] = (t >= 128 && o < 480) ? (o / 40) : -1;
  }

  // ---- j loop: 48 tiles of 16 ----
  for (int j0 = 0; j0 < 768; j0 += 16) {
    // phase b1: load pair tile (coalesced) + per-thread partial b, reduce over dq
    {
      const int j = j0 + jl;
      const float4* prow = (const float4*)(pair + ((size_t)i * 768 + j) * 128);
      float4 a0 = prow[dq * 2], a1 = prow[dq * 2 + 1];
      float4* pw = (float4*)&pairT[jl][dq * 8];
      pw[0] = a0;
      pw[1] = a1;
      float part[12];
#pragma unroll
      for (int h = 0; h < 12; h++) {
        part[h] = a0.x * wreg[h][0].x + a0.y * wreg[h][0].y +
                  a0.z * wreg[h][0].z + a0.w * wreg[h][0].w +
                  a1.x * wreg[h][1].x + a1.y * wreg[h][1].y +
                  a1.z * wreg[h][1].z + a1.w * wreg[h][1].w;
      }
#pragma unroll
      for (int m = 1; m < 16; m <<= 1) {
#pragma unroll
        for (int h = 0; h < 12; h++) part[h] += __shfl_xor(part[h], m);
      }
      if (dq == 0) {
#pragma unroll
        for (int h = 0; h < 12; h++) bbL[jl][h] = part[h];
      }
    }
    __syncthreads();

    // phase b2: logits + online softmax update (12h x 16j threads)
    if (t < 192) {
      const int h = t >> 4, jj = t & 15;
      const int j2 = j0 + jj;
      float qk = 0.f;
      const float4* k4 = (const float4*)(kbuf + (size_t)j2 * 192 + h * 16);
      const float4* q4 = (const float4*)&qL[h][0];
#pragma unroll
      for (int c4 = 0; c4 < 4; c4++) {
        float4 kv = k4[c4], qv = q4[c4];
        qk += qv.x * kv.x + qv.y * kv.y + qv.z * kv.z + qv.w * kv.w;
      }
      float cr = 0.f;
      const float4* kg4 = (const float4*)(kgbuf + (size_t)j2 * 144 + h * 12);
      const float4* qg4 = (const float4*)&qgL[h][0];
#pragma unroll
      for (int e4 = 0; e4 < 3; e4++) {
        float4 kv = kg4[e4], qv = qg4[e4];
        cr += qv.x * kv.x + qv.y * kv.y + qv.z * kv.z + qv.w * kv.w;
      }
      float d2 = sqL[h] + skbuf[j2 * 12 + h] - 2.f * cr;
      float logit = W_L_ * (INV_SQRT_C_ * qk + bbL[jj][h] - 0.5f * W_C_ * hwL[h] * d2);
      float tmax = logit;
#pragma unroll
      for (int m = 8; m >= 1; m >>= 1) tmax = fmaxf(tmax, __shfl_xor(tmax, m));
      float mold = mL[h];
      float mnew = fmaxf(mold, tmax);
      float p = __expf(logit - mnew);
      pbT[jj][h] = p;
      float ps = p;
#pragma unroll
      for (int m = 8; m >= 1; m >>= 1) ps += __shfl_xor(ps, m);
      if (jj == 0) {
        float r = __expf(mold - mnew);
        rL[h] = r;
        lL[h] = lL[h] * r + ps;
        mL[h] = mnew;
      }
    }
    __syncthreads();

    // phase e: accumulate o_pair (t<128) and o/og (t>=128)
    if (t < 128) {
#pragma unroll
      for (int h = 0; h < 12; h++) opacc[h] *= rL[h];
#pragma unroll
      for (int jj = 0; jj < 16; jj++) {
        float pv = pairT[jj][t];
        const float4* pp4 = (const float4*)&pbT[jj][0];
        float4 p0 = pp4[0], p1 = pp4[1], p2 = pp4[2];
        opacc[0] += p0.x * pv; opacc[1] += p0.y * pv;
        opacc[2] += p0.z * pv; opacc[3] += p0.w * pv;
        opacc[4] += p1.x * pv; opacc[5] += p1.y * pv;
        opacc[6] += p1.z * pv; opacc[7] += p1.w * pv;
        opacc[8] += p2.x * pv; opacc[9] += p2.y * pv;
        opacc[10] += p2.z * pv; opacc[11] += p2.w * pv;
      }
    } else {
#pragma unroll
      for (int g = 0; g < 4; g++)
        if (oh[g] >= 0) ovacc[g] *= rL[oh[g]];
      for (int jj = 0; jj < 16; jj++) {
        const float* vrow = v2buf + (size_t)(j0 + jj) * 480;
#pragma unroll
        for (int g = 0; g < 4; g++) {
          int o = u + g * 128;
          if (oh[g] >= 0) ovacc[g] += pbT[jj][oh[g]] * vrow[o];
        }
      }
    }
    __syncthreads();
  }

  // ---- finalize ----
  const size_t fbase = (size_t)i * 2112;
  if (t < 128) {
#pragma unroll
    for (int h = 0; h < 12; h++)
      feats[fbase + h * 128 + t] = opacc[h] / lL[h];  // o_pair
  } else {
#pragma unroll
    for (int g = 0; g < 4; g++) {
      int o = u + g * 128;
      if (oh[g] >= 0) oaccL[oh[g]][o % 40] = ovacc[g] / lL[oh[g]];
    }
  }
  __syncthreads();
  if (t < 192) {
    int h = t >> 4, c = t & 15;
    feats[fbase + 1536 + h * 16 + c] = oaccL[h][c];  // o scalar
  }
  if (t < 96) {
    int h = t >> 3, p = t & 7;
    float og0 = oaccL[h][16 + p * 3 + 0] - ttL[0];
    float og1 = oaccL[h][16 + p * 3 + 1] - ttL[1];
    float og2 = oaccL[h][16 + p * 3 + 2] - ttL[2];
    // ol[x] = sum_y R[y][x] * (og[y]-t[y]);  R[y][x] = RL[y*3+x]
    float o0 = RL[0] * og0 + RL[3] * og1 + RL[6] * og2;
    float o1 = RL[1] * og0 + RL[4] * og1 + RL[7] * og2;
    float o2 = RL[2] * og0 + RL[5] * og1 + RL[8] * og2;
    feats[fbase + 1728 + h * 24 + p * 3 + 0] = o0;
    feats[fbase + 1728 + h * 24 + p * 3 + 1] = o1;
    feats[fbase + 1728 + h * 24 + p * 3 + 2] = o2;
    feats[fbase + 2016 + h * 8 + p] = sqrtf(o0 * o0 + o1 * o1 + o2 * o2 + 1e-8f);
  }
}

// ---------------------------------------------------------------------------
extern "C" void kernel_launch(void* const* d_in, const int* in_sizes, int n_in,
                              void* d_out, int out_size, void* d_ws, size_t ws_size,
                              hipStream_t stream) {
  const float* single = (const float*)d_in[0];
  const float* pair = (const float*)d_in[1];
  const float* fR = (const float*)d_in[2];
  const float* ft = (const float*)d_in[3];
  const float* W_qkv = (const float*)d_in[4];
  const float* W_b = (const float*)d_in[5];
  const float* W_qkp = (const float*)d_in[6];
  const float* W_vp = (const float*)d_in[7];
  const float* gamma = (const float*)d_in[8];
  const float* W_out = (const float*)d_in[9];
  const float* b_out = (const float*)d_in[10];
  float* out = (float*)d_out;

  float* ws = (float*)d_ws;
  float* projQKV = ws;                       // 768*576
  float* projQKP = projQKV + 768 * 576;      // 768*288
  float* projVP = projQKP + 768 * 288;       // 768*288
  float* qbuf = projVP + 768 * 288;          // 768*192
  float* kbuf = qbuf + 768 * 192;            // 768*192
  float* v2buf = kbuf + 768 * 192;           // 768*480
  float* qgbuf = v2buf + 768 * 480;          // 768*144
  float* kgbuf = qgbuf + 768 * 144;          // 768*144
  float* sqbuf = kgbuf + 768 * 144;          // 768*12
  float* skbuf = sqbuf + 768 * 12;           // 768*12
  float* feats = skbuf + 768 * 12;           // 768*2112

  // projections
  gemm_tiled<<<dim3(18, 24), 256, 0, stream>>>(single, W_qkv, nullptr, projQKV, 768, 576, 384);
  gemm_tiled<<<dim3(9, 24), 256, 0, stream>>>(single, W_qkp, nullptr, projQKP, 768, 288, 384);
  gemm_tiled<<<dim3(9, 24), 256, 0, stream>>>(single, W_vp, nullptr, projVP, 768, 288, 384);
  // reshape + frames + norms
  prep_kernel<<<768, 256, 0, stream>>>(projQKV, projQKP, projVP, fR, ft,
                                       qbuf, kbuf, v2buf, qgbuf, kgbuf, sqbuf, skbuf);
  // fused attention (single pass over pair_rep)
  ipa_main<<<768, 256, 0, stream>>>(pair, W_b, gamma, fR, ft, qbuf, kbuf, v2buf,
                                    qgbuf, kgbuf, sqbuf, skbuf, feats);
  // output projection
  gemm_tiled<<<dim3(12, 24), 256, 0, stream>>>(feats, W_out, b_out, out, 768, 384, 2112);
}

// Round 2
// 434.799 us; speedup vs baseline: 6.2497x; 6.2497x over previous
//
#include <hip/hip_runtime.h>
#include <hip/hip_bf16.h>

typedef float v4f __attribute__((ext_vector_type(4)));

// IPA constants
constexpr float W_C_ = 0.23570226039551584f;  // sqrt(2/(9*4))
constexpr float W_L_ = 0.5773502691896258f;   // sqrt(1/3)

__device__ __forceinline__ float dot4(v4f a, v4f b) {
  return a.x * b.x + a.y * b.y + a.z * b.z + a.w * b.w;
}

// ---------------------------------------------------------------------------
// Generic 32x32-tile f32 GEMM: Co[M,N] = A[M,K] @ B[K,N] (+ bias[N])
// ---------------------------------------------------------------------------
__global__ __launch_bounds__(256) void gemm_tiled(
    const float* __restrict__ A, const float* __restrict__ B,
    const float* __restrict__ bias, float* __restrict__ Co,
    int M, int N, int K) {
  __shared__ float As[32][33];
  __shared__ float Bs[32][33];
  const int bi = blockIdx.y * 32, bj = blockIdx.x * 32;
  const int t = threadIdx.x;
  const int ty = t >> 4, tx = t & 15;
  float acc00 = 0.f, acc01 = 0.f, acc10 = 0.f, acc11 = 0.f;
  for (int k0 = 0; k0 < K; k0 += 32) {
#pragma unroll
    for (int q = 0; q < 4; q++) {
      int idx = t + q * 256;
      int r = idx >> 5, c = idx & 31;
      As[r][c] = A[(size_t)(bi + r) * K + k0 + c];
      Bs[r][c] = B[(size_t)(k0 + r) * N + bj + c];
    }
    __syncthreads();
#pragma unroll
    for (int kk = 0; kk < 32; kk++) {
      float a0 = As[ty * 2][kk], a1 = As[ty * 2 + 1][kk];
      float b0 = Bs[kk][tx * 2], b1 = Bs[kk][tx * 2 + 1];
      acc00 += a0 * b0; acc01 += a0 * b1;
      acc10 += a1 * b0; acc11 += a1 * b1;
    }
    __syncthreads();
  }
  int r0 = bi + ty * 2, c0 = bj + tx * 2;
  float bb0 = bias ? bias[c0] : 0.f;
  float bb1 = bias ? bias[c0 + 1] : 0.f;
  Co[(size_t)r0 * N + c0] = acc00 + bb0;
  Co[(size_t)r0 * N + c0 + 1] = acc01 + bb1;
  Co[(size_t)(r0 + 1) * N + c0] = acc10 + bb0;
  Co[(size_t)(r0 + 1) * N + c0 + 1] = acc11 + bb1;
}

// ---------------------------------------------------------------------------
// Prep: reshape projections, apply frames to points, compute sq/sk.
// qbuf/kbuf [n][h*16+c]; v2buf [n][h*40+e] (e<16: v[c], e>=16: vg[p*3+x]);
// qgbuf/kgbuf [n][h*12+e]; sqbuf/skbuf [n][12].
// ---------------------------------------------------------------------------
__global__ __launch_bounds__(256) void prep_kernel(
    const float* __restrict__ projQKV, const float* __restrict__ projQKP,
    const float* __restrict__ projVP, const float* __restrict__ fR,
    const float* __restrict__ ft,
    float* __restrict__ qbuf, float* __restrict__ kbuf, float* __restrict__ v2buf,
    float* __restrict__ qgbuf, float* __restrict__ kgbuf,
    float* __restrict__ sqbuf, float* __restrict__ skbuf) {
  const int n = blockIdx.x, t = threadIdx.x;
  __shared__ float R[9], tt[3];
  __shared__ float qgL[144], kgL[144];
  if (t < 9) R[t] = fR[n * 9 + t];
  if (t < 3) tt[t] = ft[n * 3 + t];
  __syncthreads();
  const float* rQKV = projQKV + (size_t)n * 576;
  const float* rQKP = projQKP + (size_t)n * 288;
  const float* rVP = projVP + (size_t)n * 288;
  if (t < 192) {
    int h = t >> 4, c = t & 15;
    qbuf[(size_t)n * 192 + t] = rQKV[c * 12 + h];
    kbuf[(size_t)n * 192 + t] = rQKV[192 + c * 12 + h];
    v2buf[(size_t)n * 480 + h * 40 + c] = rQKV[384 + c * 12 + h];
  }
  if (t < 144) {
    int e = t / 12, h = t % 12;
    int p = e / 3, x = e % 3;
    float aq = tt[x], ak = tt[x];
#pragma unroll
    for (int y = 0; y < 3; y++) {
      float r = R[x * 3 + y];
      aq += r * rQKP[p * 36 + y * 12 + h];
      ak += r * rQKP[144 + p * 36 + y * 12 + h];
    }
    qgL[h * 12 + e] = aq;
    kgL[h * 12 + e] = ak;
    qgbuf[(size_t)n * 144 + h * 12 + e] = aq;
    kgbuf[(size_t)n * 144 + h * 12 + e] = ak;
  }
  for (int idx = t; idx < 288; idx += 256) {
    int e = idx / 12, h = idx % 12;
    int p = e / 3, x = e % 3;
    float a = tt[x];
#pragma unroll
    for (int y = 0; y < 3; y++) a += R[x * 3 + y] * rVP[p * 36 + y * 12 + h];
    v2buf[(size_t)n * 480 + h * 40 + 16 + e] = a;
  }
  __syncthreads();
  if (t < 12) {
    float s = 0.f;
#pragma unroll
    for (int e = 0; e < 12; e++) { float v = qgL[t * 12 + e]; s += v * v; }
    sqbuf[n * 12 + t] = s;
  } else if (t < 24) {
    int h = t - 12;
    float s = 0.f;
#pragma unroll
    for (int e = 0; e < 12; e++) { float v = kgL[h * 12 + e]; s += v * v; }
    skbuf[n * 12 + h] = s;
  }
}

// ---------------------------------------------------------------------------
// Logits: block = (j-tile of 64, i). Reads pair tile once, computes
// L[i][h][j] = W_L*(qk/4 + b - 0.5*W_C*softplus(gamma)*dist2).
// Single barrier, then pure ILP. Grid 12 x 768 = 9216 blocks.
// ---------------------------------------------------------------------------
__global__ __launch_bounds__(256) void logits_k(
    const float* __restrict__ pair, const float* __restrict__ W_b,
    const float* __restrict__ gamma,
    const float* __restrict__ qbuf, const float* __restrict__ kbuf,
    const float* __restrict__ qgbuf, const float* __restrict__ kgbuf,
    const float* __restrict__ sqbuf, const float* __restrict__ skbuf,
    float* __restrict__ L) {
  const int jt = blockIdx.x, i = blockIdx.y;
  const int j0 = jt * 64;
  const int t = threadIdx.x;
  __shared__ float pairL[64][132];  // stride 132: b128 reads hit 8 bank-quads
  __shared__ float WbT[12][128];

  // stage W_b transposed: W_b[d*12+h] -> WbT[h][d]
  for (int idx = t; idx < 1536; idx += 256) {
    int d = idx / 12, h = idx % 12;
    WbT[h][d] = W_b[idx];
  }
  // stage pair tile (64 rows x 128 f, contiguous 32KB) — coalesced
  const v4f* gp = (const v4f*)(pair + ((size_t)i * 768 + j0) * 128);
#pragma unroll
  for (int it = 0; it < 8; ++it) {
    int idx = t + it * 256;
    *(v4f*)&pairL[idx >> 5][(idx & 31) * 4] = gp[idx];
  }
  __syncthreads();

  const int j = t & 63, hb = (t >> 6) * 3;  // wave-uniform hb
  const int jg = j0 + j;

  // pair-bias dots for 3 heads, one pass over the row
  float b0 = 0.f, b1 = 0.f, b2 = 0.f;
#pragma unroll
  for (int c4 = 0; c4 < 32; ++c4) {
    v4f pv = *(const v4f*)&pairL[j][c4 * 4];
    v4f w0 = *(const v4f*)&WbT[hb][c4 * 4];
    v4f w1 = *(const v4f*)&WbT[hb + 1][c4 * 4];
    v4f w2 = *(const v4f*)&WbT[hb + 2][c4 * 4];
    b0 += dot4(pv, w0);
    b1 += dot4(pv, w1);
    b2 += dot4(pv, w2);
  }

#pragma unroll
  for (int hh = 0; hh < 3; ++hh) {
    const int h = hb + hh;
    float bb = (hh == 0) ? b0 : (hh == 1) ? b1 : b2;
    float qk = 0.f;
    const v4f* q4 = (const v4f*)(qbuf + (size_t)i * 192 + h * 16);
    const v4f* k4 = (const v4f*)(kbuf + (size_t)jg * 192 + h * 16);
#pragma unroll
    for (int c = 0; c < 4; ++c) qk += dot4(q4[c], k4[c]);
    float cr = 0.f;
    const v4f* qg4 = (const v4f*)(qgbuf + (size_t)i * 144 + h * 12);
    const v4f* kg4 = (const v4f*)(kgbuf + (size_t)jg * 144 + h * 12);
#pragma unroll
    for (int e = 0; e < 3; ++e) cr += dot4(qg4[e], kg4[e]);
    float d2 = sqbuf[i * 12 + h] + skbuf[(size_t)jg * 12 + h] - 2.f * cr;
    float g = gamma[h];
    float hw = fmaxf(g, 0.f) + log1pf(expf(-fabsf(g)));  // softplus
    float logit = W_L_ * (0.25f * qk + bb - 0.5f * W_C_ * hw * d2);
    L[((size_t)i * 12 + h) * 768 + jg] = logit;
  }
}

// ---------------------------------------------------------------------------
// Softmax over j: one wave per (i,h) row of 768. In-place on L. Grid 2304.
// ---------------------------------------------------------------------------
__global__ __launch_bounds__(256) void softmax_rows(float* __restrict__ L) {
  const int row = blockIdx.x * 4 + (threadIdx.x >> 6);
  const int lane = threadIdx.x & 63;
  v4f* p = (v4f*)(L + (size_t)row * 768);
  v4f a0 = p[lane], a1 = p[lane + 64], a2 = p[lane + 128];
  float m = fmaxf(fmaxf(fmaxf(a0.x, a0.y), fmaxf(a0.z, a0.w)),
                  fmaxf(fmaxf(fmaxf(a1.x, a1.y), fmaxf(a1.z, a1.w)),
                        fmaxf(fmaxf(a2.x, a2.y), fmaxf(a2.z, a2.w))));
#pragma unroll
  for (int s = 32; s >= 1; s >>= 1) m = fmaxf(m, __shfl_xor(m, s));
  a0.x = __expf(a0.x - m); a0.y = __expf(a0.y - m);
  a0.z = __expf(a0.z - m); a0.w = __expf(a0.w - m);
  a1.x = __expf(a1.x - m); a1.y = __expf(a1.y - m);
  a1.z = __expf(a1.z - m); a1.w = __expf(a1.w - m);
  a2.x = __expf(a2.x - m); a2.y = __expf(a2.y - m);
  a2.z = __expf(a2.z - m); a2.w = __expf(a2.w - m);
  float s = a0.x + a0.y + a0.z + a0.w + a1.x + a1.y + a1.z + a1.w +
            a2.x + a2.y + a2.z + a2.w;
#pragma unroll
  for (int q = 32; q >= 1; q >>= 1) s += __shfl_xor(s, q);
  float inv = 1.f / s;
  a0 *= inv; a1 *= inv; a2 *= inv;
  p[lane] = a0; p[lane + 64] = a1; p[lane + 128] = a2;
}

// ---------------------------------------------------------------------------
// o_pair: block per i. Second (and last) pass over pair. Threads t<192 own
// (dgrp=t&15, h=t>>4), accumulate o_pair[h][dgrp*4..] over 12 j-tiles.
// Writes feats[:, 0:1536] directly (attn is already normalized).
// ---------------------------------------------------------------------------
__global__ __launch_bounds__(256) void opair_k(
    const float* __restrict__ pair, const float* __restrict__ attn,
    float* __restrict__ feats) {
  const int i = blockIdx.x, t = threadIdx.x;
  __shared__ float pairL[64][132];
  __shared__ float AL[12][68];
  const int dgrp = t & 15, h = t >> 4;
  v4f acc0 = {0.f, 0.f, 0.f, 0.f}, acc1 = {0.f, 0.f, 0.f, 0.f};
  for (int jt = 0; jt < 12; ++jt) {
    const int j0 = jt * 64;
    const v4f* gp = (const v4f*)(pair + ((size_t)i * 768 + j0) * 128);
#pragma unroll
    for (int it = 0; it < 8; ++it) {
      int idx = t + it * 256;
      *(v4f*)&pairL[idx >> 5][(idx & 31) * 4] = gp[idx];
    }
    if (t < 192) {
      *(v4f*)&AL[h][dgrp * 4] =
          *(const v4f*)(attn + ((size_t)i * 12 + h) * 768 + j0 + dgrp * 4);
    }
    __syncthreads();
    if (t < 192) {
#pragma unroll 4
      for (int jj = 0; jj < 64; ++jj) {
        float a = AL[h][jj];
        v4f p0 = *(const v4f*)&pairL[jj][dgrp * 4];
        v4f p1 = *(const v4f*)&pairL[jj][64 + dgrp * 4];
        acc0 += p0 * a;
        acc1 += p1 * a;
      }
    }
    __syncthreads();
  }
  if (t < 192) {
    float* f = feats + (size_t)i * 2112 + h * 128;
    *(v4f*)&f[dgrp * 4] = acc0;
    *(v4f*)&f[64 + dgrp * 4] = acc1;
  }
}

// ---------------------------------------------------------------------------
// o / og: batched per-head tiled "GEMM": O2[i][h][e] = sum_j A[i,h,j]*v2[j,h,e]
// Grid (12 i-tiles, 12 heads). All data L2/L3-resident.
// ---------------------------------------------------------------------------
__global__ __launch_bounds__(256) void ov_k(
    const float* __restrict__ attn, const float* __restrict__ v2buf,
    float* __restrict__ O2) {
  const int i0 = blockIdx.x * 64, h = blockIdx.y, t = threadIdx.x;
  __shared__ float AL[64][65];   // stride 65: scalar reads conflict-free
  __shared__ float VL[64][48];   // 40 e's padded to 48 (f4-aligned)
  const int il = t & 63, eb = (t >> 6) * 12;
  v4f acc0 = {0.f, 0.f, 0.f, 0.f}, acc1 = {0.f, 0.f, 0.f, 0.f},
      acc2 = {0.f, 0.f, 0.f, 0.f};
  for (int jt = 0; jt < 12; ++jt) {
    const int j0 = jt * 64;
#pragma unroll
    for (int q = 0; q < 4; q++) {
      int idx = t + q * 256;  // 0..1023
      int ii = idx >> 4, j4 = idx & 15;
      v4f a = *(const v4f*)(attn + ((size_t)(i0 + ii) * 12 + h) * 768 + j0 + j4 * 4);
      AL[ii][j4 * 4 + 0] = a.x;
      AL[ii][j4 * 4 + 1] = a.y;
      AL[ii][j4 * 4 + 2] = a.z;
      AL[ii][j4 * 4 + 3] = a.w;
    }
#pragma unroll
    for (int q = 0; q < 3; q++) {
      int idx = t + q * 256;  // need 640
      if (idx < 640) {
        int jj = idx / 10, e4 = idx % 10;
        *(v4f*)&VL[jj][e4 * 4] =
            *(const v4f*)(v2buf + (size_t)(j0 + jj) * 480 + h * 40 + e4 * 4);
      }
    }
    __syncthreads();
#pragma unroll 4
    for (int jj = 0; jj < 64; ++jj) {
      float a = AL[il][jj];
      v4f v0 = *(const v4f*)&VL[jj][eb];
      v4f v1 = *(const v4f*)&VL[jj][eb + 4];
      v4f v2 = *(const v4f*)&VL[jj][eb + 8];
      acc0 += v0 * a;
      acc1 += v1 * a;
      acc2 += v2 * a;
    }
    __syncthreads();
  }
  float* orow = O2 + ((size_t)(i0 + il) * 12 + h) * 40;
#pragma unroll
  for (int s = 0; s < 12; ++s) {
    int e = eb + s;
    if (e < 40) {
      float v = (s < 4) ? ((float*)&acc0)[s] : (s < 8) ? ((float*)&acc1)[s - 4]
                                                       : ((float*)&acc2)[s - 8];
      orow[e] = v;
    }
  }
}

// ---------------------------------------------------------------------------
// Finalize: local-frame transform + norms, writes feats[:, 1536:2112].
// ---------------------------------------------------------------------------
__global__ __launch_bounds__(256) void finalize_k(
    const float* __restrict__ O2, const float* __restrict__ fR,
    const float* __restrict__ ft, float* __restrict__ feats) {
  const int i = blockIdx.x, t = threadIdx.x;
  __shared__ float RL[9], ttL[3];
  if (t < 9) RL[t] = fR[i * 9 + t];
  if (t < 3) ttL[t] = ft[i * 3 + t];
  __syncthreads();
  const float* orow = O2 + (size_t)i * 480;
  const size_t fb = (size_t)i * 2112;
  if (t < 192) {
    int h = t >> 4, c = t & 15;
    feats[fb + 1536 + h * 16 + c] = orow[h * 40 + c];
  }
  if (t < 96) {
    int h = t >> 3, p = t & 7;
    float og0 = orow[h * 40 + 16 + p * 3 + 0] - ttL[0];
    float og1 = orow[h * 40 + 16 + p * 3 + 1] - ttL[1];
    float og2 = orow[h * 40 + 16 + p * 3 + 2] - ttL[2];
    float o0 = RL[0] * og0 + RL[3] * og1 + RL[6] * og2;
    float o1 = RL[1] * og0 + RL[4] * og1 + RL[7] * og2;
    float o2 = RL[2] * og0 + RL[5] * og1 + RL[8] * og2;
    feats[fb + 1728 + h * 24 + p * 3 + 0] = o0;
    feats[fb + 1728 + h * 24 + p * 3 + 1] = o1;
    feats[fb + 1728 + h * 24 + p * 3 + 2] = o2;
    feats[fb + 2016 + h * 8 + p] = sqrtf(o0 * o0 + o1 * o1 + o2 * o2 + 1e-8f);
  }
}

// ---------------------------------------------------------------------------
extern "C" void kernel_launch(void* const* d_in, const int* in_sizes, int n_in,
                              void* d_out, int out_size, void* d_ws, size_t ws_size,
                              hipStream_t stream) {
  const float* single = (const float*)d_in[0];
  const float* pair = (const float*)d_in[1];
  const float* fR = (const float*)d_in[2];
  const float* ft = (const float*)d_in[3];
  const float* W_qkv = (const float*)d_in[4];
  const float* W_b = (const float*)d_in[5];
  const float* W_qkp = (const float*)d_in[6];
  const float* W_vp = (const float*)d_in[7];
  const float* gamma = (const float*)d_in[8];
  const float* W_out = (const float*)d_in[9];
  const float* b_out = (const float*)d_in[10];
  float* out = (float*)d_out;

  float* ws = (float*)d_ws;
  float* projQKV = ws;                       // 768*576
  float* projQKP = projQKV + 768 * 576;      // 768*288
  float* projVP = projQKP + 768 * 288;       // 768*288
  float* qbuf = projVP + 768 * 288;          // 768*192
  float* kbuf = qbuf + 768 * 192;            // 768*192
  float* v2buf = kbuf + 768 * 192;           // 768*480
  float* qgbuf = v2buf + 768 * 480;          // 768*144
  float* kgbuf = qgbuf + 768 * 144;          // 768*144
  float* sqbuf = kgbuf + 768 * 144;          // 768*12
  float* skbuf = sqbuf + 768 * 12;           // 768*12
  float* attn = skbuf + 768 * 12;            // 768*12*768 (logits, then attn)
  float* O2 = attn + 768 * 12 * 768;         // 768*12*40
  float* feats = O2 + 768 * 12 * 40;         // 768*2112

  // projections
  gemm_tiled<<<dim3(18, 24), 256, 0, stream>>>(single, W_qkv, nullptr, projQKV, 768, 576, 384);
  gemm_tiled<<<dim3(9, 24), 256, 0, stream>>>(single, W_qkp, nullptr, projQKP, 768, 288, 384);
  gemm_tiled<<<dim3(9, 24), 256, 0, stream>>>(single, W_vp, nullptr, projVP, 768, 288, 384);
  // reshape + frames + norms
  prep_kernel<<<768, 256, 0, stream>>>(projQKV, projQKP, projVP, fR, ft,
                                       qbuf, kbuf, v2buf, qgbuf, kgbuf, sqbuf, skbuf);
  // logits (pair pass 1)
  logits_k<<<dim3(12, 768), 256, 0, stream>>>(pair, W_b, gamma, qbuf, kbuf,
                                              qgbuf, kgbuf, sqbuf, skbuf, attn);
  // softmax over j (in place)
  softmax_rows<<<2304, 256, 0, stream>>>(attn);
  // o_pair (pair pass 2) -> feats[:,0:1536]
  opair_k<<<768, 256, 0, stream>>>(pair, attn, feats);
  // o / og -> O2
  ov_k<<<dim3(12, 12), 256, 0, stream>>>(attn, v2buf, O2);
  // finalize -> feats[:,1536:2112]
  finalize_k<<<768, 256, 0, stream>>>(O2, fR, ft, feats);
  // output projection
  gemm_tiled<<<dim3(12, 24), 256, 0, stream>>>(feats, W_out, b_out, out, 768, 384, 2112);
}

// Round 3
// 310.553 us; speedup vs baseline: 8.7500x; 1.4001x over previous
//
#include <hip/hip_runtime.h>
#include <hip/hip_bf16.h>

typedef float v4f __attribute__((ext_vector_type(4)));
typedef short bf8 __attribute__((ext_vector_type(8)));  // 8 bf16 in 4 VGPRs
typedef unsigned short u16;

constexpr float W_C_ = 0.23570226039551584f;  // sqrt(2/(9*4))
constexpr float W_L_ = 0.5773502691896258f;   // sqrt(1/3)

__device__ __forceinline__ u16 f2bf(float f) {  // RNE f32->bf16
  unsigned u = __float_as_uint(f);
  return (u16)((u + 0x7FFFu + ((u >> 16) & 1u)) >> 16);
}
__device__ __forceinline__ float bf2f(u16 h) {
  return __uint_as_float(((unsigned)h) << 16);
}
__device__ __forceinline__ float dot4(v4f a, v4f b) {
  return a.x * b.x + a.y * b.y + a.z * b.z + a.w * b.w;
}

// ---------------------------------------------------------------------------
// f32 -> bf16 elementwise (n8 = n/8 chunks)
// ---------------------------------------------------------------------------
__global__ __launch_bounds__(256) void convert_bf(const float* __restrict__ src,
                                                  u16* __restrict__ dst, int n8) {
  int idx = blockIdx.x * 256 + threadIdx.x;
  if (idx < n8) {
    v4f a = ((const v4f*)src)[idx * 2];
    v4f b = ((const v4f*)src)[idx * 2 + 1];
    bf8 o;
    o[0] = (short)f2bf(a.x); o[1] = (short)f2bf(a.y);
    o[2] = (short)f2bf(a.z); o[3] = (short)f2bf(a.w);
    o[4] = (short)f2bf(b.x); o[5] = (short)f2bf(b.y);
    o[6] = (short)f2bf(b.z); o[7] = (short)f2bf(b.w);
    ((bf8*)dst)[idx] = o;
  }
}

// ---------------------------------------------------------------------------
// Pre-fragment a weight matrix W[K][N] (f32) into MFMA B-fragment order:
// frag[ks][nt][lane][e] (bf16), B[k=ks*32+(l>>4)*8+e][col=nt*16+(l&15)].
// One block per 32-k slab; column panels of <=384 staged in LDS.
// ---------------------------------------------------------------------------
__global__ __launch_bounds__(256) void wfrag_k(const float* __restrict__ W,
                                               u16* __restrict__ frag,
                                               int K, int N) {
  __shared__ float Ws[32 * 384];
  const int ks = blockIdx.x, k0 = ks * 32, t = threadIdx.x;
  const int NTfull = (N + 15) >> 4;
  for (int n0 = 0; n0 < N; n0 += 384) {
    int PN = N - n0; if (PN > 384) PN = 384;
    __syncthreads();
    for (int idx = t; idx < 32 * PN; idx += 256) {
      int r = idx / PN, c = idx - r * PN;
      Ws[r * PN + c] = W[(size_t)(k0 + r) * N + n0 + c];
    }
    __syncthreads();
    int NTp = (PN + 15) >> 4;
    for (int c = t; c < NTp * 64; c += 256) {
      int nt = c >> 6, l = c & 63;
      int col = nt * 16 + (l & 15);
      bf8 o;
#pragma unroll
      for (int e = 0; e < 8; e++) {
        int rr = (l >> 4) * 8 + e;
        float f = (col < PN) ? Ws[rr * PN + col] : 0.f;
        o[e] = (short)f2bf(f);
      }
      ((bf8*)frag)[((size_t)ks * NTfull + (n0 >> 4) + nt) * 64 + l] = o;
    }
  }
}

// ---------------------------------------------------------------------------
// f32 GEMM, BM=64 BN=32 BK=32, micro 4x2 with v4f LDS reads (point projs).
// ---------------------------------------------------------------------------
__global__ __launch_bounds__(256) void gemm_f32(
    const float* __restrict__ A, const float* __restrict__ B,
    float* __restrict__ C, int M, int N, int K) {
  __shared__ float AsT[32][68];  // [k][row]
  __shared__ float Bs[32][36];
  const int bi = blockIdx.y * 64, bj = blockIdx.x * 32;
  const int t = threadIdx.x, ty = t >> 4, tx = t & 15;
  v4f acc0 = {0.f, 0.f, 0.f, 0.f}, acc1 = {0.f, 0.f, 0.f, 0.f};
  for (int k0 = 0; k0 < K; k0 += 32) {
#pragma unroll
    for (int q = 0; q < 2; q++) {
      int idx = t + 256 * q;
      int row = idx >> 3, c4 = idx & 7;
      v4f av = *(const v4f*)(A + (size_t)(bi + row) * K + k0 + c4 * 4);
      AsT[c4 * 4 + 0][row] = av.x;
      AsT[c4 * 4 + 1][row] = av.y;
      AsT[c4 * 4 + 2][row] = av.z;
      AsT[c4 * 4 + 3][row] = av.w;
    }
    {
      int r = t >> 3, c4 = t & 7;
      *(v4f*)&Bs[r][c4 * 4] = *(const v4f*)(B + (size_t)(k0 + r) * N + bj + c4 * 4);
    }
    __syncthreads();
#pragma unroll
    for (int kk = 0; kk < 32; kk++) {
      v4f a = *(const v4f*)&AsT[kk][ty * 4];
      float b0 = Bs[kk][tx * 2], b1 = Bs[kk][tx * 2 + 1];
      acc0 += a * b0;
      acc1 += a * b1;
    }
    __syncthreads();
  }
#pragma unroll
  for (int e = 0; e < 4; e++) {
    int row = bi + ty * 4 + e;
    C[(size_t)row * N + bj + tx * 2] = acc0[e];
    C[(size_t)row * N + bj + tx * 2 + 1] = acc1[e];
  }
}

// ---------------------------------------------------------------------------
// bf16 MFMA GEMM: C[M][ldc](f32) = Abf[M][K] @ Bfrag + bias. BM=64 BN=32.
// B-fragments direct from global (pre-fragmented); A staged with chunk-XOR.
// ---------------------------------------------------------------------------
__global__ __launch_bounds__(256) void mfma_gemm(
    const u16* __restrict__ Abf, const u16* __restrict__ Bfrag,
    const float* __restrict__ bias, float* __restrict__ C,
    int M, int N, int K, int ldc) {
  __shared__ u16 As[64 * 32];
  const int t = threadIdx.x, w = t >> 6, l = t & 63;
  const int bi = blockIdx.y * 64, nt0 = blockIdx.x * 2;
  const int NT = N >> 4, KS = K >> 5;
  v4f acc0 = {0.f, 0.f, 0.f, 0.f}, acc1 = {0.f, 0.f, 0.f, 0.f};
  const int srow = t >> 2, sc = t & 3;
  const int wslot = (sc ^ (srow & 3)) * 8;
  const bf8* Bf = (const bf8*)Bfrag;

  bf8 areg = *(const bf8*)(Abf + (size_t)(bi + srow) * K + sc * 8);
  bf8 b0 = Bf[(size_t)(0 * NT + nt0) * 64 + l];
  bf8 b1 = Bf[(size_t)(0 * NT + nt0 + 1) * 64 + l];
  const int rdoff = (w * 16 + (l & 15)) * 32 + (((l >> 4) ^ (l & 3)) * 8);
  for (int ks = 0; ks < KS; ks++) {
    *(bf8*)&As[srow * 32 + wslot] = areg;
    bf8 an, bn0, bn1;
    if (ks + 1 < KS) {
      an = *(const bf8*)(Abf + (size_t)(bi + srow) * K + (ks + 1) * 32 + sc * 8);
      bn0 = Bf[(size_t)((ks + 1) * NT + nt0) * 64 + l];
      bn1 = Bf[(size_t)((ks + 1) * NT + nt0 + 1) * 64 + l];
    }
    __syncthreads();
    bf8 af = *(const bf8*)&As[rdoff];
    acc0 = __builtin_amdgcn_mfma_f32_16x16x32_bf16(af, b0, acc0, 0, 0, 0);
    acc1 = __builtin_amdgcn_mfma_f32_16x16x32_bf16(af, b1, acc1, 0, 0, 0);
    __syncthreads();
    areg = an; b0 = bn0; b1 = bn1;
  }
  int col0 = nt0 * 16 + (l & 15), col1 = col0 + 16;
  float bb0 = bias ? bias[col0] : 0.f;
  float bb1 = bias ? bias[col1] : 0.f;
#pragma unroll
  for (int r = 0; r < 4; r++) {
    int row = bi + w * 16 + (l >> 4) * 4 + r;
    C[(size_t)row * ldc + col0] = acc0[r] + bb0;
    C[(size_t)row * ldc + col1] = acc1[r] + bb1;
  }
}

// ---------------------------------------------------------------------------
// Prep: reshape projections, apply frames, build kTT[h][e][j] (e: 0-15 k,
// 16-27 kg, 28 sk), qbuf [n][h*16+c], qgbuf [n][h*12+e], sqbuf, v2buf.
// ---------------------------------------------------------------------------
__global__ __launch_bounds__(256) void prep_kernel(
    const float* __restrict__ projQKV, const float* __restrict__ projQKP,
    const float* __restrict__ projVP, const float* __restrict__ fR,
    const float* __restrict__ ft,
    float* __restrict__ qbuf, float* __restrict__ v2buf,
    float* __restrict__ qgbuf, float* __restrict__ sqbuf,
    float* __restrict__ kTT) {
  const int n = blockIdx.x, t = threadIdx.x;
  __shared__ float R[9], tt[3];
  __shared__ float qgL[144], kgL[144];
  if (t < 9) R[t] = fR[n * 9 + t];
  if (t < 3) tt[t] = ft[n * 3 + t];
  __syncthreads();
  const float* rQKV = projQKV + (size_t)n * 576;
  const float* rQKP = projQKP + (size_t)n * 288;
  const float* rVP = projVP + (size_t)n * 288;
  if (t < 192) {
    int h = t >> 4, c = t & 15;
    qbuf[(size_t)n * 192 + t] = rQKV[c * 12 + h];
    kTT[(size_t)(h * 29 + c) * 768 + n] = rQKV[192 + c * 12 + h];
    v2buf[(size_t)n * 480 + h * 40 + c] = rQKV[384 + c * 12 + h];
  }
  if (t < 144) {
    int e = t / 12, h = t % 12;
    int p = e / 3, x = e % 3;
    float aq = tt[x], ak = tt[x];
#pragma unroll
    for (int y = 0; y < 3; y++) {
      float r = R[x * 3 + y];
      aq += r * rQKP[p * 36 + y * 12 + h];
      ak += r * rQKP[144 + p * 36 + y * 12 + h];
    }
    qgL[h * 12 + e] = aq;
    kgL[h * 12 + e] = ak;
    qgbuf[(size_t)n * 144 + h * 12 + e] = aq;
    kTT[(size_t)(h * 29 + 16 + e) * 768 + n] = ak;
  }
  for (int idx = t; idx < 288; idx += 256) {
    int e = idx / 12, h = idx % 12;
    int p = e / 3, x = e % 3;
    float a = tt[x];
#pragma unroll
    for (int y = 0; y < 3; y++) a += R[x * 3 + y] * rVP[p * 36 + y * 12 + h];
    v2buf[(size_t)n * 480 + h * 40 + 16 + e] = a;
  }
  __syncthreads();
  if (t < 12) {
    float s = 0.f;
#pragma unroll
    for (int e = 0; e < 12; e++) { float v = qgL[t * 12 + e]; s += v * v; }
    sqbuf[n * 12 + t] = s;
  } else if (t < 24) {
    int h = t - 12;
    float s = 0.f;
#pragma unroll
    for (int e = 0; e < 12; e++) { float v = kgL[h * 12 + e]; s += v * v; }
    kTT[(size_t)(h * 29 + 28) * 768 + n] = s;
  }
}

// ---------------------------------------------------------------------------
// Pair-bias via MFMA: b[i][h][j](bf16) = pair[i,j,:128] @ W_b. Pass 1 of pair.
// Block = (jt, i): 64 j-rows. A = pair rows (k=d contiguous), chunk-XOR LDS.
// ---------------------------------------------------------------------------
__global__ __launch_bounds__(256) void bias_mfma(
    const float* __restrict__ pair, const u16* __restrict__ WbFrag,
    u16* __restrict__ bbuf) {
  const int jt = blockIdx.x, i = blockIdx.y;
  const int t = threadIdx.x, w = t >> 6, l = t & 63;
  __shared__ u16 pS[64 * 128];  // [j][slot*8] bf16
  bf8 bf[4];
  const bf8* Wf = (const bf8*)WbFrag;
#pragma unroll
  for (int ks = 0; ks < 4; ks++) bf[ks] = Wf[ks * 64 + l];
  const float* pg = pair + ((size_t)i * 768 + jt * 64) * 128;
#pragma unroll
  for (int it = 0; it < 4; it++) {
    int idx = t + 256 * it;
    int j = idx >> 4, c = idx & 15;
    v4f x0 = *(const v4f*)(pg + j * 128 + c * 8);
    v4f x1 = *(const v4f*)(pg + j * 128 + c * 8 + 4);
    bf8 pk;
    pk[0] = (short)f2bf(x0.x); pk[1] = (short)f2bf(x0.y);
    pk[2] = (short)f2bf(x0.z); pk[3] = (short)f2bf(x0.w);
    pk[4] = (short)f2bf(x1.x); pk[5] = (short)f2bf(x1.y);
    pk[6] = (short)f2bf(x1.z); pk[7] = (short)f2bf(x1.w);
    *(bf8*)&pS[j * 128 + ((c ^ (j & 15)) * 8)] = pk;
  }
  __syncthreads();
  v4f acc = {0.f, 0.f, 0.f, 0.f};
#pragma unroll
  for (int ks = 0; ks < 4; ks++) {
    int slot = (ks * 4 + (l >> 4)) ^ (l & 15);
    bf8 af = *(const bf8*)&pS[(w * 16 + (l & 15)) * 128 + slot * 8];
    acc = __builtin_amdgcn_mfma_f32_16x16x32_bf16(af, bf[ks], acc, 0, 0, 0);
  }
  int h = l & 15;
  if (h < 12) {
    int jbase = jt * 64 + w * 16 + (l >> 4) * 4;
    u16* dst = bbuf + ((size_t)i * 12 + h) * 768 + jbase;
#pragma unroll
    for (int r = 0; r < 4; r++) dst[r] = f2bf(acc[r]);
  }
}

// ---------------------------------------------------------------------------
// Logits (qk + point-dist + bias) and softmax, fused. Block = (h, i).
// All k-side loads lane-coalesced from kTT. Writes attn bf16 [i][h][j].
// ---------------------------------------------------------------------------
__global__ __launch_bounds__(256) void qk_softmax(
    const float* __restrict__ qbuf, const float* __restrict__ qgbuf,
    const float* __restrict__ sqbuf, const float* __restrict__ kTT,
    const u16* __restrict__ bbuf, const float* __restrict__ gamma,
    u16* __restrict__ attn) {
  const int h = blockIdx.x, i = blockIdx.y, t = threadIdx.x;
  __shared__ float red[8];
  float q[16], qg[12];
  const float* qb = qbuf + (size_t)i * 192 + h * 16;
  const float* qgb = qgbuf + (size_t)i * 144 + h * 12;
#pragma unroll
  for (int c = 0; c < 16; c++) q[c] = qb[c];
#pragma unroll
  for (int e = 0; e < 12; e++) qg[e] = qgb[e];
  float sq = sqbuf[i * 12 + h];
  float g = gamma[h];
  float hw = fmaxf(g, 0.f) + log1pf(expf(-fabsf(g)));
  const float* kb = kTT + (size_t)h * 29 * 768;
  const u16* brow = bbuf + ((size_t)i * 12 + h) * 768;
  float lg[3];
#pragma unroll
  for (int s = 0; s < 3; s++) {
    int j = t + 256 * s;
    float qk = 0.f;
#pragma unroll
    for (int c = 0; c < 16; c++) qk += q[c] * kb[c * 768 + j];
    float cr = 0.f;
#pragma unroll
    for (int e = 0; e < 12; e++) cr += qg[e] * kb[(16 + e) * 768 + j];
    float sk = kb[28 * 768 + j];
    float b = bf2f(brow[j]);
    float d2 = sq + sk - 2.f * cr;
    lg[s] = W_L_ * (0.25f * qk + b - 0.5f * W_C_ * hw * d2);
  }
  float m = fmaxf(fmaxf(lg[0], lg[1]), lg[2]);
#pragma unroll
  for (int o = 32; o >= 1; o >>= 1) m = fmaxf(m, __shfl_xor(m, o));
  if ((t & 63) == 0) red[t >> 6] = m;
  __syncthreads();
  m = fmaxf(fmaxf(red[0], red[1]), fmaxf(red[2], red[3]));
  float p0 = __expf(lg[0] - m), p1 = __expf(lg[1] - m), p2 = __expf(lg[2] - m);
  float ss = p0 + p1 + p2;
#pragma unroll
  for (int o = 32; o >= 1; o >>= 1) ss += __shfl_xor(ss, o);
  if ((t & 63) == 0) red[4 + (t >> 6)] = ss;
  __syncthreads();
  float inv = 1.f / (red[4] + red[5] + red[6] + red[7]);
  u16* arow = attn + ((size_t)i * 12 + h) * 768;
  arow[t] = f2bf(p0 * inv);
  arow[t + 256] = f2bf(p1 * inv);
  arow[t + 512] = f2bf(p2 * inv);
}

// ---------------------------------------------------------------------------
// o_pair: pass 2 of pair. Block per i. Each wave reads a pair row ONCE
// (b128, 2-lane broadcast covers 128 d), lane holds 4d x 6h f32 accs,
// waves split jj; cross-wave LDS reduce at end. Double-buffered staging.
// ---------------------------------------------------------------------------
__global__ __launch_bounds__(256) void opair_k(
    const float* __restrict__ pair, const u16* __restrict__ attn,
    u16* __restrict__ feats_bf) {
  const int i = blockIdx.x, t = threadIdx.x;
  const int w = t >> 6, l = t & 63;
  const int dq = l & 31, hh = l >> 5;
  __shared__ float pairL[64][132];
  __shared__ float ALf[12][68];
  v4f acc[6];
#pragma unroll
  for (int k = 0; k < 6; k++) acc[k] = (v4f){0.f, 0.f, 0.f, 0.f};

  v4f pr[8];
  bf8 areg;
  {
    const float* pg = pair + ((size_t)i * 768) * 128;
#pragma unroll
    for (int it = 0; it < 8; it++) {
      int idx = t + 256 * it;
      pr[it] = *(const v4f*)(pg + (idx >> 5) * 128 + (idx & 31) * 4);
    }
    if (t < 96)
      areg = *(const bf8*)(attn + ((size_t)i * 12 + (t >> 3)) * 768 + (t & 7) * 8);
  }
  for (int jt = 0; jt < 12; jt++) {
#pragma unroll
    for (int it = 0; it < 8; it++) {
      int idx = t + 256 * it;
      *(v4f*)&pairL[idx >> 5][(idx & 31) * 4] = pr[it];
    }
    if (t < 96) {
      int hA = t >> 3, c = t & 7;
#pragma unroll
      for (int e = 0; e < 8; e++) ALf[hA][c * 8 + e] = bf2f((u16)areg[e]);
    }
    if (jt < 11) {
      const float* pg = pair + ((size_t)i * 768 + (jt + 1) * 64) * 128;
#pragma unroll
      for (int it = 0; it < 8; it++) {
        int idx = t + 256 * it;
        pr[it] = *(const v4f*)(pg + (idx >> 5) * 128 + (idx & 31) * 4);
      }
      if (t < 96)
        areg = *(const bf8*)(attn + ((size_t)i * 12 + (t >> 3)) * 768 +
                             (jt + 1) * 64 + (t & 7) * 8);
    }
    __syncthreads();
#pragma unroll
    for (int jj16 = 0; jj16 < 16; jj16++) {
      int jj = w * 16 + jj16;
      v4f pv = *(const v4f*)&pairL[jj][dq * 4];
      float a0 = ALf[hh * 6 + 0][jj];
      float a1 = ALf[hh * 6 + 1][jj];
      float a2 = ALf[hh * 6 + 2][jj];
      float a3 = ALf[hh * 6 + 3][jj];
      float a4 = ALf[hh * 6 + 4][jj];
      float a5 = ALf[hh * 6 + 5][jj];
      acc[0] += pv * a0; acc[1] += pv * a1; acc[2] += pv * a2;
      acc[3] += pv * a3; acc[4] += pv * a4; acc[5] += pv * a5;
    }
    __syncthreads();
  }
  // cross-wave reduction (overlay on pairL)
  float* red = &pairL[0][0];  // 4*12*128 = 6144 floats < 64*132
#pragma unroll
  for (int k = 0; k < 6; k++)
    *(v4f*)&red[((w * 12 + hh * 6 + k) << 7) + dq * 4] = acc[k];
  __syncthreads();
  const size_t fb = (size_t)i * 2112;
#pragma unroll
  for (int s = 0; s < 6; s++) {
    int o = t + 256 * s;  // h = o>>7, d = o&127
    int ho = o >> 7, dd = o & 127;
    float v = red[(ho << 7) + dd] + red[((12 + ho) << 7) + dd] +
              red[((24 + ho) << 7) + dd] + red[((36 + ho) << 7) + dd];
    feats_bf[fb + o] = f2bf(v);
  }
}

// ---------------------------------------------------------------------------
// o / og: O2[i][h][e] = sum_j attn[i,h,j]*v2[j,h,e]. Grid (12 i-tiles, 12 h).
// ---------------------------------------------------------------------------
__global__ __launch_bounds__(256) void ov_k(
    const u16* __restrict__ attn, const float* __restrict__ v2buf,
    float* __restrict__ O2) {
  const int i0 = blockIdx.x * 64, h = blockIdx.y, t = threadIdx.x;
  __shared__ float AL[64][65];
  __shared__ float VL[64][48];
  const int il = t & 63, eb = (t >> 6) * 12;
  v4f acc0 = {0.f, 0.f, 0.f, 0.f}, acc1 = {0.f, 0.f, 0.f, 0.f},
      acc2 = {0.f, 0.f, 0.f, 0.f};
  for (int jt = 0; jt < 12; ++jt) {
    const int j0 = jt * 64;
#pragma unroll
    for (int q = 0; q < 2; q++) {
      int idx = t + 256 * q;
      int ii = idx >> 3, c = idx & 7;
      bf8 av = *(const bf8*)(attn + ((size_t)(i0 + ii) * 12 + h) * 768 + j0 + c * 8);
#pragma unroll
      for (int e = 0; e < 8; e++) AL[ii][c * 8 + e] = bf2f((u16)av[e]);
    }
#pragma unroll
    for (int q = 0; q < 3; q++) {
      int idx = t + q * 256;
      if (idx < 640) {
        int jj = idx / 10, e4 = idx % 10;
        *(v4f*)&VL[jj][e4 * 4] =
            *(const v4f*)(v2buf + (size_t)(j0 + jj) * 480 + h * 40 + e4 * 4);
      }
    }
    __syncthreads();
#pragma unroll 4
    for (int jj = 0; jj < 64; ++jj) {
      float a = AL[il][jj];
      v4f v0 = *(const v4f*)&VL[jj][eb];
      v4f v1 = *(const v4f*)&VL[jj][eb + 4];
      v4f v2 = *(const v4f*)&VL[jj][eb + 8];
      acc0 += v0 * a;
      acc1 += v1 * a;
      acc2 += v2 * a;
    }
    __syncthreads();
  }
  float* orow = O2 + ((size_t)(i0 + il) * 12 + h) * 40;
#pragma unroll
  for (int s = 0; s < 12; ++s) {
    int e = eb + s;
    if (e < 40) {
      float v = (s < 4) ? ((float*)&acc0)[s]
                        : (s < 8) ? ((float*)&acc1)[s - 4] : ((float*)&acc2)[s - 8];
      orow[e] = v;
    }
  }
}

// ---------------------------------------------------------------------------
// Finalize: local-frame transform + norms -> feats_bf[:, 1536:2112].
// ---------------------------------------------------------------------------
__global__ __launch_bounds__(256) void finalize_k(
    const float* __restrict__ O2, const float* __restrict__ fR,
    const float* __restrict__ ft, u16* __restrict__ feats_bf) {
  const int i = blockIdx.x, t = threadIdx.x;
  __shared__ float RL[9], ttL[3];
  if (t < 9) RL[t] = fR[i * 9 + t];
  if (t < 3) ttL[t] = ft[i * 3 + t];
  __syncthreads();
  const float* orow = O2 + (size_t)i * 480;
  const size_t fb = (size_t)i * 2112;
  if (t < 192) {
    int h = t >> 4, c = t & 15;
    feats_bf[fb + 1536 + h * 16 + c] = f2bf(orow[h * 40 + c]);
  }
  if (t < 96) {
    int h = t >> 3, p = t & 7;
    float og0 = orow[h * 40 + 16 + p * 3 + 0] - ttL[0];
    float og1 = orow[h * 40 + 16 + p * 3 + 1] - ttL[1];
    float og2 = orow[h * 40 + 16 + p * 3 + 2] - ttL[2];
    float o0 = RL[0] * og0 + RL[3] * og1 + RL[6] * og2;
    float o1 = RL[1] * og0 + RL[4] * og1 + RL[7] * og2;
    float o2 = RL[2] * og0 + RL[5] * og1 + RL[8] * og2;
    feats_bf[fb + 1728 + h * 24 + p * 3 + 0] = f2bf(o0);
    feats_bf[fb + 1728 + h * 24 + p * 3 + 1] = f2bf(o1);
    feats_bf[fb + 1728 + h * 24 + p * 3 + 2] = f2bf(o2);
    feats_bf[fb + 2016 + h * 8 + p] = f2bf(sqrtf(o0 * o0 + o1 * o1 + o2 * o2 + 1e-8f));
  }
}

// ---------------------------------------------------------------------------
extern "C" void kernel_launch(void* const* d_in, const int* in_sizes, int n_in,
                              void* d_out, int out_size, void* d_ws, size_t ws_size,
                              hipStream_t stream) {
  const float* single = (const float*)d_in[0];
  const float* pair = (const float*)d_in[1];
  const float* fR = (const float*)d_in[2];
  const float* ft = (const float*)d_in[3];
  const float* W_qkv = (const float*)d_in[4];
  const float* W_b = (const float*)d_in[5];
  const float* W_qkp = (const float*)d_in[6];
  const float* W_vp = (const float*)d_in[7];
  const float* gamma = (const float*)d_in[8];
  const float* W_out = (const float*)d_in[9];
  const float* b_out = (const float*)d_in[10];
  float* out = (float*)d_out;

  float* ws = (float*)d_ws;
  float* projQKV = ws;                        // 768*576
  float* projQKP = projQKV + 442368;          // 768*288
  float* projVP  = projQKP + 221184;          // 768*288
  float* qbuf    = projVP + 221184;           // 768*192
  float* v2buf   = qbuf + 147456;             // 768*480
  float* qgbuf   = v2buf + 368640;            // 768*144
  float* sqbuf   = qgbuf + 110592;            // 768*12
  float* kTT     = sqbuf + 9216;              // 12*29*768
  float* O2      = kTT + 267264;              // 768*480
  u16* single_bf = (u16*)(O2 + 368640);       // 768*384
  u16* WqkvFrag  = single_bf + 294912;        // 384*576
  u16* WbFrag    = WqkvFrag + 221184;         // 128*16
  u16* WoutFrag  = WbFrag + 2048;             // 2112*384
  u16* bbuf      = WoutFrag + 811008;         // 768*12*768
  u16* attn      = bbuf + 7077888;            // 768*12*768
  u16* feats_bf  = attn + 7077888;            // 768*2112

  // weight fragmenting + input conversion
  convert_bf<<<144, 256, 0, stream>>>(single, single_bf, 36864);
  wfrag_k<<<12, 256, 0, stream>>>(W_qkv, WqkvFrag, 384, 576);
  wfrag_k<<<4, 256, 0, stream>>>(W_b, WbFrag, 128, 12);
  wfrag_k<<<66, 256, 0, stream>>>(W_out, WoutFrag, 2112, 384);
  // point projections (f32 for precision)
  gemm_f32<<<dim3(9, 12), 256, 0, stream>>>(single, W_qkp, projQKP, 768, 288, 384);
  gemm_f32<<<dim3(9, 12), 256, 0, stream>>>(single, W_vp, projVP, 768, 288, 384);
  // scalar qkv projection (bf16 MFMA)
  mfma_gemm<<<dim3(18, 12), 256, 0, stream>>>(single_bf, WqkvFrag, nullptr,
                                              projQKV, 768, 576, 384, 576);
  // reshape + frames + transposed k-layout
  prep_kernel<<<768, 256, 0, stream>>>(projQKV, projQKP, projVP, fR, ft,
                                       qbuf, v2buf, qgbuf, sqbuf, kTT);
  // pair pass 1: pair-bias via MFMA
  bias_mfma<<<dim3(12, 768), 256, 0, stream>>>(pair, WbFrag, bbuf);
  // logits + softmax fused
  qk_softmax<<<dim3(12, 768), 256, 0, stream>>>(qbuf, qgbuf, sqbuf, kTT, bbuf,
                                                gamma, attn);
  // pair pass 2: o_pair
  opair_k<<<768, 256, 0, stream>>>(pair, attn, feats_bf);
  // o / og
  ov_k<<<dim3(12, 12), 256, 0, stream>>>(attn, v2buf, O2);
  // local frames + norms
  finalize_k<<<768, 256, 0, stream>>>(O2, fR, ft, feats_bf);
  // output projection (bf16 MFMA)
  mfma_gemm<<<dim3(12, 12), 256, 0, stream>>>(feats_bf, WoutFrag, b_out,
                                              out, 768, 384, 2112, 384);
}